// Round 1
// baseline (309.337 us; speedup 1.0000x reference)
//
#include <hip/hip_runtime.h>
#include <cstdint>
#include <cstddef>

#define T_SEQ 2048
#define B_SZ  2
#define EMB   2048
#define NH    16
#define NKV   4
#define HD    128
#define KVD   512
#define QKVN  3072
#define MROWS (B_SZ*T_SEQ)

typedef __bf16 bf16x8 __attribute__((ext_vector_type(8)));
typedef float  f32x4  __attribute__((ext_vector_type(4)));
typedef short  s16x8  __attribute__((ext_vector_type(8)));
typedef unsigned short u16;

__device__ __forceinline__ u16 f2b(float f) {
  uint32_t u = __builtin_bit_cast(uint32_t, f);
  u += 0x7fffu + ((u >> 16) & 1u);      // RNE
  return (u16)(u >> 16);
}
__device__ __forceinline__ float b2f(u16 h) {
  return __builtin_bit_cast(float, (uint32_t)h << 16);
}
__device__ __forceinline__ bf16x8 ld_bf8(const u16* p) {
  return __builtin_bit_cast(bf16x8, *(const s16x8*)p);
}
__device__ __forceinline__ void glds16(const void* g, void* l) {
  __builtin_amdgcn_global_load_lds((const __attribute__((address_space(1))) void*)g,
                                   (__attribute__((address_space(3))) void*)l, 16, 0, 0);
}

// ---------------- fp32 -> bf16 elementwise ----------------
__global__ void cvt_x_kernel(const float4* __restrict__ x, ushort4* __restrict__ xb, int n4) {
  int i = blockIdx.x*blockDim.x + threadIdx.x;
  if (i >= n4) return;
  float4 v = x[i];
  ushort4 o;
  o.x = f2b(v.x); o.y = f2b(v.y); o.z = f2b(v.z); o.w = f2b(v.w);
  xb[i] = o;
}

// ---------------- fp32 (R x C) -> bf16 transposed (C x R) ----------------
__global__ void transpose_w_kernel(const float* __restrict__ in, u16* __restrict__ out,
                                   int R, int C) {
  __shared__ float tile[32][33];
  int c0 = blockIdx.x*32, r0 = blockIdx.y*32;
  int tx = threadIdx.x, ty = threadIdx.y;
#pragma unroll
  for (int i = 0; i < 32; i += 8)
    tile[ty+i][tx] = in[(size_t)(r0+ty+i)*C + c0+tx];
  __syncthreads();
#pragma unroll
  for (int i = 0; i < 32; i += 8)
    out[(size_t)(c0+ty+i)*R + r0+tx] = f2b(tile[tx][ty+i]);
}

// ---------------- bf16 GEMM, 256x256 tile, 8-phase counted-vmcnt schedule ----
// C(MxN) = A(MxK) * Bt(NxK)^T (+bias). 512 threads = 8 waves (2 row x 4 col),
// per-wave output 128x64 -> acc[8][4]. BK=64, double-buffered LDS (128 KiB).
// XOR chunk swizzle (carried over, measured conflict-free): global 16B-chunk
// `pos` of row r lands at LDS pos `pos ^ (r&7)`; frag reads XOR the same.
//
// Schedule ledger (T3+T4+T5 per the 8-phase template):
//   per K-tile: ph{A0-3,B0-1 -> Q00}{B2-3 -> Q02}{A4-7 -> Q40}{- -> Q42}
//   buf.B fully read after ph2, buf.A after ph3 (wave wr touches only A-half wr,
//   wave wc only its 64-row B band). Issue slots (1 half-tile = 2 glds/thd):
//   ph1,2: A(t1)->buf1 | ph3,4: B(t0+2)->buf0 | ph5,6: A(t0+2)->buf0 |
//   ph7,8: B(t1+2)->buf1. Each issue is after the barrier following the last
//   read of its target region. vmcnt(4) at ph4 (drains tile t1) and ph8
//   (drains tile t0+2); never vmcnt(0) in the main loop. Tail iteration
//   computes the last 2 tiles with one vmcnt(0).
template<bool BF16_OUT>
__global__ __launch_bounds__(512, 2) void gemm256_kernel(const u16* __restrict__ A,
        const u16* __restrict__ Bt, const float* __restrict__ bias,
        void* __restrict__ Cout, int M, int N, int K) {
  __shared__ u16 As[2][16384];   // [buf][256 rows][64] (half h at rows h*128..)
  __shared__ u16 Bs[2][16384];
  const int tid = threadIdx.x;
  const int w = tid >> 6, lane = tid & 63;
  const int quad = lane >> 4, lc = lane & 15;
  const int wr = w >> 2, wc = w & 3;
  const int m0 = blockIdx.y*256, n0 = blockIdx.x*256;

  f32x4 acc[8][4] = {};
  bf16x8 af[4][2], bfv[4][2];

  // frag-read chunk offsets (row&7 == lc&7 since wr*128, wc*64, i*16 are 0 mod 8)
  int aoff[2];
#pragma unroll
  for (int ks = 0; ks < 2; ++ks) aoff[ks] = ((ks*4 + quad) ^ (lc & 7))*8;
  const int arow = (wr*128 + lc)*64;
  const int brow = (wc*64  + lc)*64;

  // staging: chunk c = r*512 + tid (r=0,1), row = c>>3 (0..127 within half),
  // source chunk pos = (c&7) ^ (row&7)  [inverse of the read-side XOR]
  const int r0 = tid >> 3,          p0 = (tid & 7) ^ (r0 & 7);
  const int r1 = (tid + 512) >> 3,  p1 = (tid & 7) ^ (r1 & 7);
  const u16* sa0 = A  + (size_t)(m0 + r0)*K + p0*8;
  const u16* sa1 = A  + (size_t)(m0 + r1)*K + p1*8;
  const u16* sb0 = Bt + (size_t)(n0 + r0)*K + p0*8;
  const u16* sb1 = Bt + (size_t)(n0 + r1)*K + p1*8;
  const int wch = w*512;  // wave's u16 chunk base within an r-block

#define STAGE_A(bf_, h_, t_) do { \
    glds16(sa0 + (size_t)(h_)*128*K + (t_)*64, &As[bf_][(h_)*8192 + wch]); \
    glds16(sa1 + (size_t)(h_)*128*K + (t_)*64, &As[bf_][(h_)*8192 + 4096 + wch]); \
  } while (0)
#define STAGE_B(bf_, h_, t_) do { \
    glds16(sb0 + (size_t)(h_)*128*K + (t_)*64, &Bs[bf_][(h_)*8192 + wch]); \
    glds16(sb1 + (size_t)(h_)*128*K + (t_)*64, &Bs[bf_][(h_)*8192 + 4096 + wch]); \
  } while (0)
#define LDA03(S) do { _Pragma("unroll") for (int i = 0; i < 4; ++i) { \
    af[i][0] = ld_bf8((S) + arow + i*1024 + aoff[0]); \
    af[i][1] = ld_bf8((S) + arow + i*1024 + aoff[1]); } } while (0)
#define LDA47(S) do { _Pragma("unroll") for (int i = 0; i < 4; ++i) { \
    af[i][0] = ld_bf8((S) + arow + 4096 + i*1024 + aoff[0]); \
    af[i][1] = ld_bf8((S) + arow + 4096 + i*1024 + aoff[1]); } } while (0)
#define LDB01(S) do { _Pragma("unroll") for (int j = 0; j < 2; ++j) { \
    bfv[j][0] = ld_bf8((S) + brow + j*1024 + aoff[0]); \
    bfv[j][1] = ld_bf8((S) + brow + j*1024 + aoff[1]); } } while (0)
#define LDB23(S) do { _Pragma("unroll") for (int j = 2; j < 4; ++j) { \
    bfv[j][0] = ld_bf8((S) + brow + j*1024 + aoff[0]); \
    bfv[j][1] = ld_bf8((S) + brow + j*1024 + aoff[1]); } } while (0)
#define QUAD(ib_, jb_) do { _Pragma("unroll") for (int ks = 0; ks < 2; ++ks) \
    _Pragma("unroll") for (int i = 0; i < 4; ++i) \
    _Pragma("unroll") for (int j = 0; j < 2; ++j) \
      acc[(ib_)+i][(jb_)+j] = __builtin_amdgcn_mfma_f32_16x16x32_bf16( \
          af[i][ks], bfv[(jb_)+j][ks], acc[(ib_)+i][(jb_)+j], 0, 0, 0); } while (0)
#define BARX()  __builtin_amdgcn_s_barrier()
#define SCHB()  __builtin_amdgcn_sched_barrier(0)
#define VMCNT(n_) do { asm volatile("s_waitcnt vmcnt(" #n_ ")" ::: "memory"); SCHB(); } while (0)
// barrier -> lgkmcnt(0)+sched_barrier (rule #18) -> setprio(1) MFMA setprio(0)
#define MFMAPH(ib_, jb_) do { BARX(); \
    asm volatile("s_waitcnt lgkmcnt(0)" ::: "memory"); SCHB(); \
    __builtin_amdgcn_s_setprio(1); QUAD(ib_, jb_); __builtin_amdgcn_s_setprio(0); \
  } while (0)

  const int NT = K >> 6;   // K-tiles of 64
  // prologue: tile0 (all 4 half-tiles) + B(tile1); drain tile0, keep B(1) in flight
  STAGE_A(0, 0, 0); STAGE_A(0, 1, 0); STAGE_B(0, 0, 0); STAGE_B(0, 1, 0);
  STAGE_B(1, 0, 1); STAGE_B(1, 1, 1);
  VMCNT(4);
  BARX(); SCHB();

  for (int t0 = 0; t0 < NT-2; t0 += 2) {
    const int t1 = t0 + 1;
    const u16 *a0 = As[0], *b0 = Bs[0], *a1 = As[1], *b1 = Bs[1];
    // ph1
    LDA03(a0); LDB01(b0); STAGE_A(1, 0, t1);
    MFMAPH(0, 0); BARX();
    // ph2
    LDB23(b0); STAGE_A(1, 1, t1);
    MFMAPH(0, 2); BARX();
    // ph3
    LDA47(a0); STAGE_B(0, 0, t0+2);
    MFMAPH(4, 0); BARX();
    // ph4  (drain tile t1 for ph5; 2 half-tiles stay in flight)
    STAGE_B(0, 1, t0+2);
    MFMAPH(4, 2);
    VMCNT(4);
    BARX(); SCHB();
    // ph5
    LDA03(a1); LDB01(b1); STAGE_A(0, 0, t0+2);
    MFMAPH(0, 0); BARX();
    // ph6
    LDB23(b1); STAGE_A(0, 1, t0+2);
    MFMAPH(0, 2); BARX();
    // ph7
    LDA47(a1); STAGE_B(1, 0, t1+2);
    MFMAPH(4, 0); BARX();
    // ph8  (drain tile t0+2 for next iteration's ph1)
    STAGE_B(1, 1, t1+2);
    MFMAPH(4, 2);
    VMCNT(4);
    BARX(); SCHB();
  }
  // tail: tiles NT-2 (buf0), NT-1 (buf1); no further prefetch
  {
    const u16 *a0 = As[0], *b0 = Bs[0], *a1 = As[1], *b1 = Bs[1];
    LDA03(a0); LDB01(b0); STAGE_A(1, 0, NT-1);
    MFMAPH(0, 0); BARX();
    LDB23(b0); STAGE_A(1, 1, NT-1);
    MFMAPH(0, 2); BARX();
    LDA47(a0);
    MFMAPH(4, 0); BARX();
    MFMAPH(4, 2);
    VMCNT(0);
    BARX(); SCHB();
    LDA03(a1); LDB01(b1);
    MFMAPH(0, 0); BARX();
    LDB23(b1);
    MFMAPH(0, 2); BARX();
    LDA47(a1);
    MFMAPH(4, 0); BARX();
    MFMAPH(4, 2);
  }

#undef STAGE_A
#undef STAGE_B
#undef LDA03
#undef LDA47
#undef LDB01
#undef LDB23
#undef QUAD
#undef BARX
#undef SCHB
#undef VMCNT
#undef MFMAPH

  // epilogue
#pragma unroll
  for (int j = 0; j < 4; ++j) {
    int col = n0 + wc*64 + j*16 + lc;
    float bv = BF16_OUT ? bias[col] : 0.0f;
#pragma unroll
    for (int i = 0; i < 8; ++i) {
      int rowb = m0 + wr*128 + i*16 + quad*4;
#pragma unroll
      for (int r = 0; r < 4; ++r) {
        float v = acc[i][j][r] + bv;
        if (BF16_OUT) ((u16*)Cout)[(size_t)(rowb+r)*N + col] = f2b(v);
        else          ((float*)Cout)[(size_t)(rowb+r)*N + col] = v;
      }
    }
  }
}

// ---------------- RoPE on K and V (reference ropes V too, not Q) ----------------
__global__ void rope_kernel(const u16* __restrict__ qkv, const float* __restrict__ fc,
                            const float* __restrict__ fs, u16* __restrict__ kout,
                            u16* __restrict__ vout) {
  int tid = threadIdx.x;
  int row = blockIdx.x;             // b*T + t
  int i = tid & 63, kv = tid >> 6;  // pair index, kv head
  int t = row & (T_SEQ-1);
  const u16* p = qkv + (size_t)row*QKVN + EMB + kv*HD + 2*i;
  float ka = b2f(p[0]),   kb = b2f(p[1]);
  float va = b2f(p[KVD]), vb = b2f(p[KVD+1]);
  float c = fc[t*64+i], s = fs[t*64+i];
  size_t ob = (size_t)row*KVD + kv*HD + 2*i;
  kout[ob]   = f2b(ka*c - kb*s);
  kout[ob+1] = f2b(ka*s + kb*c);
  vout[ob]   = f2b(va*c - vb*s);
  vout[ob+1] = f2b(va*s + vb*c);
}

// ---------------- V (b,t,kv,d) -> Vt (b,kv,d,t) ----------------
__global__ void transpose_v_kernel(const u16* __restrict__ vb, u16* __restrict__ vtb) {
  __shared__ u16 tile[32][33];
  int bkv = blockIdx.z;
  int b = bkv >> 2, kv = bkv & 3;
  int d0 = blockIdx.y*32, t0 = blockIdx.x*32;
  int tx = threadIdx.x, ty = threadIdx.y;
#pragma unroll
  for (int i = 0; i < 32; i += 8)
    tile[ty+i][tx] = vb[(size_t)(b*T_SEQ + t0+ty+i)*KVD + kv*HD + d0 + tx];
  __syncthreads();
#pragma unroll
  for (int i = 0; i < 32; i += 8)
    vtb[(size_t)(bkv*HD + d0+ty+i)*T_SEQ + t0 + tx] = tile[tx][ty+i];
}

// ---------------- flash attention v4: GQA-shared LDS staging ----------------
__global__ __launch_bounds__(256, 3) void flash_kernel(const u16* __restrict__ qkv,
    const u16* __restrict__ kb, const u16* __restrict__ vtb, u16* __restrict__ yb) {
  constexpr int PP = 72;                 // P pitch: 144B rows, conflict-free pa reads
  __shared__ u16 Ks[64*128];             // 16 KB
  __shared__ u16 Vs[128*64];             // 16 KB
  __shared__ u16 Ps[4][16*PP];           // 9 KB
  const int tid = threadIdx.x;
  const int w = tid >> 6, lane = tid & 63;
  const int quad = lane >> 4, lc = lane & 15;
  const int bkv = blockIdx.x & 7;        // XCD-pinned (b,kv)
  const int r_  = blockIdx.x >> 3;       // 0..127
  const int b = bkv >> 2, kv = bkv & 3;
  const int h = kv*4 + w;                // wave = one head of the group
  const int qbase = (127 - r_)*16;       // heavy q-tiles dispatch first

  // Q frags (A-layout) for 16 queries of head h; no RoPE on Q
  bf16x8 qf[4];
  {
    const u16* qp = qkv + (size_t)(b*T_SEQ + qbase + lc)*QKVN + h*HD + quad*8;
#pragma unroll
    for (int ks = 0; ks < 4; ++ks) qf[ks] = ld_bf8(qp + ks*32);
  }

  f32x4 o[8] = {};
  float rs[4] = {0.f, 0.f, 0.f, 0.f};
  const u16* kbase = kb  + (size_t)b*T_SEQ*KVD + kv*HD;
  const u16* vbase = vtb + (size_t)bkv*HD*T_SEQ;
  const int nk = qbase + 16;
  const float cs = 0.08838834764831845f * 1.4426950408889634f;  // scale * log2(e)
  u16* pw = Ps[w];

  // per-lane swizzled chunk offsets (hoisted out of the K-loop)
  int koff[4], voff[2];
#pragma unroll
  for (int ks = 0; ks < 4; ++ks) koff[ks] = lc*128 + (((ks*4 + quad) ^ lc)*8);
#pragma unroll
  for (int ks = 0; ks < 2; ++ks) voff[ks] = lc*64 + (((ks*4 + quad) ^ (lc & 7))*8);

  for (int k0 = 0; k0 < nk; k0 += 64) {
    __syncthreads();
    // stage K tile: 1024 16B-chunks, 4 glds16/thread, source-side XOR swizzle
#pragma unroll
    for (int rr = 0; rr < 4; ++rr) {
      int krow = (rr*4 + w)*4 + (lane >> 4);
      int ccg  = (lane & 15) ^ (krow & 15);
      glds16(kbase + (size_t)(k0 + krow)*KVD + ccg*8, Ks + (size_t)(rr*4 + w)*512);
    }
    // stage Vt tile
#pragma unroll
    for (int rr = 0; rr < 4; ++rr) {
      int vrow = (rr*4 + w)*8 + (lane >> 3);
      int ccg  = (lane & 7) ^ (vrow & 7);
      glds16(vbase + (size_t)vrow*T_SEQ + k0 + ccg*8, Vs + (size_t)(rr*4 + w)*512);
    }
    __syncthreads();

    // S = Q K^T : 16 queries x 64 keys
    f32x4 sc[4] = {};
#pragma unroll
    for (int nt = 0; nt < 4; ++nt)
#pragma unroll
      for (int ks = 0; ks < 4; ++ks) {
        bf16x8 kf = ld_bf8(Ks + nt*16*128 + koff[ks]);
        sc[nt] = __builtin_amdgcn_mfma_f32_16x16x32_bf16(qf[ks], kf, sc[nt], 0, 0, 0);
      }

    // softmax (m=0): p = exp2(s*cs); mask only on the diagonal tile
    if (k0 + 63 > qbase) {
#pragma unroll
      for (int nt = 0; nt < 4; ++nt) {
        int key = k0 + nt*16 + lc;
        int qrow = qbase + quad*4;
#pragma unroll
        for (int r = 0; r < 4; ++r) {
          float p = (key <= qrow + r) ? exp2f(sc[nt][r]*cs) : 0.0f;
          rs[r] += p;
          pw[(quad*4 + r)*PP + nt*16 + lc] = f2b(p);
        }
      }
    } else {
#pragma unroll
      for (int nt = 0; nt < 4; ++nt)
#pragma unroll
        for (int r = 0; r < 4; ++r) {
          float p = exp2f(sc[nt][r]*cs);
          rs[r] += p;
          pw[(quad*4 + r)*PP + nt*16 + lc] = f2b(p);
        }
    }

    // P: C-layout -> A-layout via per-wave LDS roundtrip (intra-wave DS in-order)
    bf16x8 pa[2];
#pragma unroll
    for (int ks = 0; ks < 2; ++ks)
      pa[ks] = ld_bf8(pw + lc*PP + ks*32 + quad*8);

    // O += P V
#pragma unroll
    for (int j = 0; j < 8; ++j)
#pragma unroll
      for (int ks = 0; ks < 2; ++ks) {
        bf16x8 vf = ld_bf8(Vs + j*16*64 + voff[ks]);
        o[j] = __builtin_amdgcn_mfma_f32_16x16x32_bf16(pa[ks], vf, o[j], 0, 0, 0);
      }
  }

  // epilogue: l-reduce over the 16 key-lanes, normalize, store
#pragma unroll
  for (int r = 0; r < 4; ++r) {
    float v = rs[r];
#pragma unroll
    for (int off2 = 8; off2 >= 1; off2 >>= 1)
      v += __shfl_xor(v, off2);
    float inv = 1.0f / v;
    size_t orow = (size_t)(b*T_SEQ + qbase + quad*4 + r)*EMB + h*HD;
#pragma unroll
    for (int j = 0; j < 8; ++j)
      yb[orow + j*16 + lc] = f2b(o[j][r]*inv);
  }
}

extern "C" void kernel_launch(void* const* d_in, const int* in_sizes, int n_in,
                              void* d_out, int out_size, void* d_ws, size_t ws_size,
                              hipStream_t stream) {
  const float* x      = (const float*)d_in[0];
  const float* W_attn = (const float*)d_in[1];
  const float* b_attn = (const float*)d_in[2];
  const float* W_proj = (const float*)d_in[3];
  const float* fc     = (const float*)d_in[4];
  const float* fs     = (const float*)d_in[5];

  u16* ws   = (u16*)d_ws;
  u16* xb   = ws;                          // 8.39M elems  (later aliased by yb)
  u16* WaT  = xb   + (size_t)MROWS*EMB;    // 6.29M        (later aliased by WpT)
  u16* qkv  = WaT  + (size_t)QKVN*EMB;     // 12.58M
  u16* kbuf = qkv  + (size_t)MROWS*QKVN;   // 2.10M
  u16* vb   = kbuf + (size_t)MROWS*KVD;    // 2.10M
  u16* vtb  = vb   + (size_t)MROWS*KVD;    // 2.10M  -> total 67.1 MB
  u16* WpT  = WaT;   // W_attn^T dead after gemm1
  u16* yb   = xb;    // x_bf16 dead after gemm1
  float* out = (float*)d_out;

  cvt_x_kernel<<<(MROWS*EMB/4 + 255)/256, 256, 0, stream>>>(
      (const float4*)x, (ushort4*)xb, MROWS*EMB/4);
  transpose_w_kernel<<<dim3(QKVN/32, EMB/32), dim3(32, 8), 0, stream>>>(
      W_attn, WaT, EMB, QKVN);
  gemm256_kernel<true><<<dim3(QKVN/256, MROWS/256), 512, 0, stream>>>(
      xb, WaT, b_attn, qkv, MROWS, QKVN, EMB);
  rope_kernel<<<MROWS, 256, 0, stream>>>(qkv, fc, fs, kbuf, vb);
  transpose_v_kernel<<<dim3(T_SEQ/32, HD/32, B_SZ*NKV), dim3(32, 8), 0, stream>>>(vb, vtb);
  transpose_w_kernel<<<dim3(EMB/32, EMB/32), dim3(32, 8), 0, stream>>>(
      W_proj, WpT, EMB, EMB);
  flash_kernel<<<dim3(B_SZ*NKV*(T_SEQ/16)), 256, 0, stream>>>(qkv, kbuf, vtb, yb);
  gemm256_kernel<false><<<dim3(EMB/256, MROWS/256), 512, 0, stream>>>(
      yb, WpT, nullptr, out, MROWS, EMB, EMB);
}

// Round 2
// 285.325 us; speedup vs baseline: 1.0842x; 1.0842x over previous
//
#include <hip/hip_runtime.h>
#include <cstdint>
#include <cstddef>

#define T_SEQ 2048
#define B_SZ  2
#define EMB   2048
#define NH    16
#define NKV   4
#define HD    128
#define KVD   512
#define QKVN  3072
#define MROWS (B_SZ*T_SEQ)

typedef __bf16 bf16x8 __attribute__((ext_vector_type(8)));
typedef float  f32x4  __attribute__((ext_vector_type(4)));
typedef short  s16x8  __attribute__((ext_vector_type(8)));
typedef unsigned short u16;

__device__ __forceinline__ u16 f2b(float f) {
  uint32_t u = __builtin_bit_cast(uint32_t, f);
  u += 0x7fffu + ((u >> 16) & 1u);      // RNE
  return (u16)(u >> 16);
}
__device__ __forceinline__ float b2f(u16 h) {
  return __builtin_bit_cast(float, (uint32_t)h << 16);
}
__device__ __forceinline__ bf16x8 ld_bf8(const u16* p) {
  return __builtin_bit_cast(bf16x8, *(const s16x8*)p);
}
__device__ __forceinline__ void glds16(const void* g, void* l) {
  __builtin_amdgcn_global_load_lds((const __attribute__((address_space(1))) void*)g,
                                   (__attribute__((address_space(3))) void*)l, 16, 0, 0);
}
template<int N> __device__ __forceinline__ void waitv() {
  if constexpr (N == 0) asm volatile("s_waitcnt vmcnt(0)" ::: "memory");
  else if constexpr (N == 2) asm volatile("s_waitcnt vmcnt(2)" ::: "memory");
  else if constexpr (N == 3) asm volatile("s_waitcnt vmcnt(3)" ::: "memory");
  __builtin_amdgcn_sched_barrier(0);
}

// ---------------- fp32 -> bf16 elementwise ----------------
__global__ void cvt_x_kernel(const float4* __restrict__ x, ushort4* __restrict__ xb, int n4) {
  int i = blockIdx.x*blockDim.x + threadIdx.x;
  if (i >= n4) return;
  float4 v = x[i];
  ushort4 o;
  o.x = f2b(v.x); o.y = f2b(v.y); o.z = f2b(v.z); o.w = f2b(v.w);
  xb[i] = o;
}

// ---------------- fp32 (R x C) -> bf16 transposed (C x R) ----------------
__global__ void transpose_w_kernel(const float* __restrict__ in, u16* __restrict__ out,
                                   int R, int C) {
  __shared__ float tile[32][33];
  int c0 = blockIdx.x*32, r0 = blockIdx.y*32;
  int tx = threadIdx.x, ty = threadIdx.y;
#pragma unroll
  for (int i = 0; i < 32; i += 8)
    tile[ty+i][tx] = in[(size_t)(r0+ty+i)*C + c0+tx];
  __syncthreads();
#pragma unroll
  for (int i = 0; i < 32; i += 8)
    out[(size_t)(c0+ty+i)*R + r0+tx] = f2b(tile[tx][ty+i]);
}

// ---------------- bf16 GEMM, 256xBN tile, 8-phase counted-vmcnt schedule ----
// C(MxN) = A(MxK) * Bt(NxK)^T (+bias). 512 threads = 8 waves arranged
// (8/WGN) x WGN; per-wave output MF*16 x NF*16. BK=64, double-buffered LDS.
// Both instantiations give grid = 16x16 = 256 blocks = 1 block/CU (the r1
// regression was gemm2 at 128 blocks = 50% CU coverage).
//   gemm1: BN=192, 2x4 waves, per-wave 128x48, acc[8][3]
//   gemm2: BN=128, 4x2 waves, per-wave  64x64, acc[4][4]
// XOR chunk swizzle (verified conflict-free, SQ_LDS_BANK_CONFLICT=0 in r0/r1):
// global 16B-chunk g of row r lands at LDS chunk g^(r&7); reads XOR the same.
// Schedule ledger (identical lifetime structure to the verified r1 kernel):
//   per K-tile: ph1{af_h0+bfv_g0 -> CL(0,0)} ph2{bfv_g1 -> CL(0,1)}
//               ph3{af_h1 -> CL(1,0)}        ph4{       CL(1,1)}
//   buf.B fully read after ph2, buf.A after ph3. Stage slots:
//   ph1,2: A(t1)->buf1 | ph3,4: B(t0+2)->buf0 | ph5,6: A(t0+2)->buf0 |
//   ph7,8: B(t1+2)->buf1 — each after the barrier following the last read
//   of its region. Publish waits: vmcnt(SB) at ph4-end (drains A(t1),B(t1);
//   leaves B(t0+2)) and at ph8-end (drains A,B(t0+2); leaves B(t1+2)).
//   Never vmcnt(0) in the main loop; prefetch leads 2-5 phases.
template<int BN, int WGN, int MF, int NF, int NF1, int SB, int SB1, int VMC, bool BF16_OUT>
__global__ __launch_bounds__(512, 2) void gemm_kernel(const u16* __restrict__ A,
        const u16* __restrict__ Bt, const float* __restrict__ bias,
        void* __restrict__ Cout, int M, int N, int K) {
  constexpr int MF2 = MF/2;
  __shared__ u16 As[2][256*64];
  __shared__ u16 Bs[2][BN*64];
  const int tid = threadIdx.x;
  const int w = tid >> 6, lane = tid & 63;
  const int quad = lane >> 4, lc = lane & 15;
  const int wrow = w / WGN, wcol = w % WGN;
  // bijective XCD swizzle: 256 blocks, 8 XCDs -> 32 consecutive tiles each
  // (2 full M-rows of tiles: A-panel becomes L2-resident per XCD)
  const int gx = gridDim.x;
  const int lin = blockIdx.y*gx + blockIdx.x;
  const int swz = (lin & 7)*32 + (lin >> 3);
  const int m0 = (swz / gx)*256, n0 = (swz % gx)*BN;

  f32x4 acc[MF][NF] = {};
  bf16x8 af[MF2][2], bfv[NF][2];

  // frag-read chunk offsets (row&7 == lc&7: all row bases are 0 mod 8)
  int xoff[2];
#pragma unroll
  for (int ks = 0; ks < 2; ++ks) xoff[ks] = ((ks*4 + quad) ^ (lc & 7))*8;
  const int arow0 = (wrow*MF*16 + lc)*64;
  const int brow0 = (wcol*NF*16 + lc)*64;

  // staging: chunk c = r*512 + tid, srow = c>>3 = r*64 + (tid>>3),
  // source chunk pos = (c&7) ^ (srow&7)  (r-independent since r*512%8==0)
  const int srb  = tid >> 3;
  const int spos = (tid & 7) ^ (srb & 7);
  const u16* sAp = A  + (size_t)(m0 + srb)*K + spos*8;
  const u16* sBp = Bt + (size_t)(n0 + srb)*K + spos*8;

#define STAGE_A(bf_, t_, h_) do { \
    glds16(sAp + (size_t)((h_)*2  )*64*K + (size_t)(t_)*64, &As[bf_][((h_)*2  )*4096 + w*512]); \
    glds16(sAp + (size_t)((h_)*2+1)*64*K + (size_t)(t_)*64, &As[bf_][((h_)*2+1)*4096 + w*512]); \
  } while (0)
#define STAGE_B(bf_, t_, p_) do { \
    _Pragma("unroll") for (int r = (p_) ? SB1 : 0; r < ((p_) ? SB : SB1); ++r) \
      glds16(sBp + (size_t)r*64*K + (size_t)(t_)*64, &Bs[bf_][r*4096 + w*512]); \
  } while (0)
#define LDAH(S_, h_) do { _Pragma("unroll") for (int i = 0; i < MF2; ++i) { \
    af[i][0] = ld_bf8((S_) + arow0 + ((h_)*MF2 + i)*1024 + xoff[0]); \
    af[i][1] = ld_bf8((S_) + arow0 + ((h_)*MF2 + i)*1024 + xoff[1]); } } while (0)
#define LDBG(S_, g_) do { _Pragma("unroll") for (int j = (g_) ? NF1 : 0; j < ((g_) ? NF : NF1); ++j) { \
    bfv[j][0] = ld_bf8((S_) + brow0 + j*1024 + xoff[0]); \
    bfv[j][1] = ld_bf8((S_) + brow0 + j*1024 + xoff[1]); } } while (0)
#define CL(h_, g_) do { _Pragma("unroll") for (int ks = 0; ks < 2; ++ks) \
    _Pragma("unroll") for (int i = 0; i < MF2; ++i) \
    _Pragma("unroll") for (int j = (g_) ? NF1 : 0; j < ((g_) ? NF : NF1); ++j) \
      acc[(h_)*MF2+i][j] = __builtin_amdgcn_mfma_f32_16x16x32_bf16( \
          af[i][ks], bfv[j][ks], acc[(h_)*MF2+i][j], 0, 0, 0); } while (0)
#define BARX()  __builtin_amdgcn_s_barrier()
#define SCHB()  __builtin_amdgcn_sched_barrier(0)
#define MFMAPH(h_, g_) do { BARX(); \
    asm volatile("s_waitcnt lgkmcnt(0)" ::: "memory"); SCHB(); \
    __builtin_amdgcn_s_setprio(1); CL(h_, g_); __builtin_amdgcn_s_setprio(0); \
  } while (0)

  const int NT = K >> 6;   // K-tiles of 64
  // prologue: queue order mimics steady state: [B(0)] [A(0)] [B(1)]
  STAGE_B(0, 0, 0); STAGE_B(0, 0, 1);
  STAGE_A(0, 0, 0); STAGE_A(0, 0, 1);
  STAGE_B(1, 1, 0); STAGE_B(1, 1, 1);
  waitv<VMC>();            // drain B(0),A(0); keep B(1) in flight
  BARX(); SCHB();

  for (int t0 = 0; t0 < NT-2; t0 += 2) {
    const u16 *a0 = As[0], *b0 = Bs[0], *a1 = As[1], *b1 = Bs[1];
    // ph1
    LDAH(a0, 0); LDBG(b0, 0); STAGE_A(1, t0+1, 0);
    MFMAPH(0, 0); BARX();
    // ph2
    LDBG(b0, 1); STAGE_A(1, t0+1, 1);
    MFMAPH(0, 1); BARX();
    // ph3
    LDAH(a0, 1); STAGE_B(0, t0+2, 0);
    MFMAPH(1, 0); BARX();
    // ph4: publish buf1 (A(t1),B(t1)) for ph5; leave B(t0+2) in flight
    STAGE_B(0, t0+2, 1);
    MFMAPH(1, 1);
    waitv<VMC>();
    BARX(); SCHB();
    // ph5
    LDAH(a1, 0); LDBG(b1, 0); STAGE_A(0, t0+2, 0);
    MFMAPH(0, 0); BARX();
    // ph6
    LDBG(b1, 1); STAGE_A(0, t0+2, 1);
    MFMAPH(0, 1); BARX();
    // ph7
    LDAH(a1, 1); STAGE_B(1, t0+3, 0);
    MFMAPH(1, 0); BARX();
    // ph8: publish buf0 (A,B(t0+2)); leave B(t0+3) in flight
    STAGE_B(1, t0+3, 1);
    MFMAPH(1, 1);
    waitv<VMC>();
    BARX(); SCHB();
  }
  // tail: tiles NT-2 (buf0), NT-1 (buf1); only A(NT-1) still to stage
  {
    const u16 *a0 = As[0], *b0 = Bs[0], *a1 = As[1], *b1 = Bs[1];
    LDAH(a0, 0); LDBG(b0, 0); STAGE_A(1, NT-1, 0);
    MFMAPH(0, 0); BARX();
    LDBG(b0, 1); STAGE_A(1, NT-1, 1);
    MFMAPH(0, 1); BARX();
    LDAH(a0, 1);
    MFMAPH(1, 0); BARX();
    MFMAPH(1, 1);
    waitv<0>();
    BARX(); SCHB();
    LDAH(a1, 0); LDBG(b1, 0);
    MFMAPH(0, 0); BARX();
    LDBG(b1, 1);
    MFMAPH(0, 1); BARX();
    LDAH(a1, 1);
    MFMAPH(1, 0); BARX();
    MFMAPH(1, 1);
  }

#undef STAGE_A
#undef STAGE_B
#undef LDAH
#undef LDBG
#undef CL
#undef BARX
#undef SCHB
#undef MFMAPH

  // epilogue
#pragma unroll
  for (int j = 0; j < NF; ++j) {
    int col = n0 + wcol*NF*16 + j*16 + lc;
    float bv = BF16_OUT ? bias[col] : 0.0f;
#pragma unroll
    for (int i = 0; i < MF; ++i) {
      int rowb = m0 + wrow*MF*16 + i*16 + quad*4;
#pragma unroll
      for (int r = 0; r < 4; ++r) {
        float v = acc[i][j][r] + bv;
        if (BF16_OUT) ((u16*)Cout)[(size_t)(rowb+r)*N + col] = f2b(v);
        else          ((float*)Cout)[(size_t)(rowb+r)*N + col] = v;
      }
    }
  }
}

// ---------------- RoPE on K and V (reference ropes V too, not Q) ----------------
__global__ void rope_kernel(const u16* __restrict__ qkv, const float* __restrict__ fc,
                            const float* __restrict__ fs, u16* __restrict__ kout,
                            u16* __restrict__ vout) {
  int tid = threadIdx.x;
  int row = blockIdx.x;             // b*T + t
  int i = tid & 63, kv = tid >> 6;  // pair index, kv head
  int t = row & (T_SEQ-1);
  const u16* p = qkv + (size_t)row*QKVN + EMB + kv*HD + 2*i;
  float ka = b2f(p[0]),   kb = b2f(p[1]);
  float va = b2f(p[KVD]), vb = b2f(p[KVD+1]);
  float c = fc[t*64+i], s = fs[t*64+i];
  size_t ob = (size_t)row*KVD + kv*HD + 2*i;
  kout[ob]   = f2b(ka*c - kb*s);
  kout[ob+1] = f2b(ka*s + kb*c);
  vout[ob]   = f2b(va*c - vb*s);
  vout[ob+1] = f2b(va*s + vb*c);
}

// ---------------- V (b,t,kv,d) -> Vt (b,kv,d,t) ----------------
__global__ void transpose_v_kernel(const u16* __restrict__ vb, u16* __restrict__ vtb) {
  __shared__ u16 tile[32][33];
  int bkv = blockIdx.z;
  int b = bkv >> 2, kv = bkv & 3;
  int d0 = blockIdx.y*32, t0 = blockIdx.x*32;
  int tx = threadIdx.x, ty = threadIdx.y;
#pragma unroll
  for (int i = 0; i < 32; i += 8)
    tile[ty+i][tx] = vb[(size_t)(b*T_SEQ + t0+ty+i)*KVD + kv*HD + d0 + tx];
  __syncthreads();
#pragma unroll
  for (int i = 0; i < 32; i += 8)
    vtb[(size_t)(bkv*HD + d0+ty+i)*T_SEQ + t0 + tx] = tile[tx][ty+i];
}

// ---------------- flash attention v4: GQA-shared LDS staging ----------------
__global__ __launch_bounds__(256, 3) void flash_kernel(const u16* __restrict__ qkv,
    const u16* __restrict__ kb, const u16* __restrict__ vtb, u16* __restrict__ yb) {
  constexpr int PP = 72;                 // P pitch: 144B rows, conflict-free pa reads
  __shared__ u16 Ks[64*128];             // 16 KB
  __shared__ u16 Vs[128*64];             // 16 KB
  __shared__ u16 Ps[4][16*PP];           // 9 KB
  const int tid = threadIdx.x;
  const int w = tid >> 6, lane = tid & 63;
  const int quad = lane >> 4, lc = lane & 15;
  const int bkv = blockIdx.x & 7;        // XCD-pinned (b,kv)
  const int r_  = blockIdx.x >> 3;       // 0..127
  const int b = bkv >> 2, kv = bkv & 3;
  const int h = kv*4 + w;                // wave = one head of the group
  const int qbase = (127 - r_)*16;       // heavy q-tiles dispatch first

  // Q frags (A-layout) for 16 queries of head h; no RoPE on Q
  bf16x8 qf[4];
  {
    const u16* qp = qkv + (size_t)(b*T_SEQ + qbase + lc)*QKVN + h*HD + quad*8;
#pragma unroll
    for (int ks = 0; ks < 4; ++ks) qf[ks] = ld_bf8(qp + ks*32);
  }

  f32x4 o[8] = {};
  float rs[4] = {0.f, 0.f, 0.f, 0.f};
  const u16* kbase = kb  + (size_t)b*T_SEQ*KVD + kv*HD;
  const u16* vbase = vtb + (size_t)bkv*HD*T_SEQ;
  const int nk = qbase + 16;
  const float cs = 0.08838834764831845f * 1.4426950408889634f;  // scale * log2(e)
  u16* pw = Ps[w];

  // per-lane swizzled chunk offsets (hoisted out of the K-loop)
  int koff[4], voff[2];
#pragma unroll
  for (int ks = 0; ks < 4; ++ks) koff[ks] = lc*128 + (((ks*4 + quad) ^ lc)*8);
#pragma unroll
  for (int ks = 0; ks < 2; ++ks) voff[ks] = lc*64 + (((ks*4 + quad) ^ (lc & 7))*8);

  for (int k0 = 0; k0 < nk; k0 += 64) {
    __syncthreads();
    // stage K tile: 1024 16B-chunks, 4 glds16/thread, source-side XOR swizzle
#pragma unroll
    for (int rr = 0; rr < 4; ++rr) {
      int krow = (rr*4 + w)*4 + (lane >> 4);
      int ccg  = (lane & 15) ^ (krow & 15);
      glds16(kbase + (size_t)(k0 + krow)*KVD + ccg*8, Ks + (size_t)(rr*4 + w)*512);
    }
    // stage Vt tile
#pragma unroll
    for (int rr = 0; rr < 4; ++rr) {
      int vrow = (rr*4 + w)*8 + (lane >> 3);
      int ccg  = (lane & 7) ^ (vrow & 7);
      glds16(vbase + (size_t)vrow*T_SEQ + k0 + ccg*8, Vs + (size_t)(rr*4 + w)*512);
    }
    __syncthreads();

    // S = Q K^T : 16 queries x 64 keys
    f32x4 sc[4] = {};
#pragma unroll
    for (int nt = 0; nt < 4; ++nt)
#pragma unroll
      for (int ks = 0; ks < 4; ++ks) {
        bf16x8 kf = ld_bf8(Ks + nt*16*128 + koff[ks]);
        sc[nt] = __builtin_amdgcn_mfma_f32_16x16x32_bf16(qf[ks], kf, sc[nt], 0, 0, 0);
      }

    // softmax (m=0): p = exp2(s*cs); mask only on the diagonal tile
    if (k0 + 63 > qbase) {
#pragma unroll
      for (int nt = 0; nt < 4; ++nt) {
        int key = k0 + nt*16 + lc;
        int qrow = qbase + quad*4;
#pragma unroll
        for (int r = 0; r < 4; ++r) {
          float p = (key <= qrow + r) ? exp2f(sc[nt][r]*cs) : 0.0f;
          rs[r] += p;
          pw[(quad*4 + r)*PP + nt*16 + lc] = f2b(p);
        }
      }
    } else {
#pragma unroll
      for (int nt = 0; nt < 4; ++nt)
#pragma unroll
        for (int r = 0; r < 4; ++r) {
          float p = exp2f(sc[nt][r]*cs);
          rs[r] += p;
          pw[(quad*4 + r)*PP + nt*16 + lc] = f2b(p);
        }
    }

    // P: C-layout -> A-layout via per-wave LDS roundtrip (intra-wave DS in-order)
    bf16x8 pa[2];
#pragma unroll
    for (int ks = 0; ks < 2; ++ks)
      pa[ks] = ld_bf8(pw + lc*PP + ks*32 + quad*8);

    // O += P V
#pragma unroll
    for (int j = 0; j < 8; ++j)
#pragma unroll
      for (int ks = 0; ks < 2; ++ks) {
        bf16x8 vf = ld_bf8(Vs + j*16*64 + voff[ks]);
        o[j] = __builtin_amdgcn_mfma_f32_16x16x32_bf16(pa[ks], vf, o[j], 0, 0, 0);
      }
  }

  // epilogue: l-reduce over the 16 key-lanes, normalize, store
#pragma unroll
  for (int r = 0; r < 4; ++r) {
    float v = rs[r];
#pragma unroll
    for (int off2 = 8; off2 >= 1; off2 >>= 1)
      v += __shfl_xor(v, off2);
    float inv = 1.0f / v;
    size_t orow = (size_t)(b*T_SEQ + qbase + quad*4 + r)*EMB + h*HD;
#pragma unroll
    for (int j = 0; j < 8; ++j)
      yb[orow + j*16 + lc] = f2b(o[j][r]*inv);
  }
}

extern "C" void kernel_launch(void* const* d_in, const int* in_sizes, int n_in,
                              void* d_out, int out_size, void* d_ws, size_t ws_size,
                              hipStream_t stream) {
  const float* x      = (const float*)d_in[0];
  const float* W_attn = (const float*)d_in[1];
  const float* b_attn = (const float*)d_in[2];
  const float* W_proj = (const float*)d_in[3];
  const float* fc     = (const float*)d_in[4];
  const float* fs     = (const float*)d_in[5];

  u16* ws   = (u16*)d_ws;
  u16* xb   = ws;                          // 8.39M elems  (later aliased by yb)
  u16* WaT  = xb   + (size_t)MROWS*EMB;    // 6.29M        (later aliased by WpT)
  u16* qkv  = WaT  + (size_t)QKVN*EMB;     // 12.58M
  u16* kbuf = qkv  + (size_t)MROWS*QKVN;   // 2.10M
  u16* vb   = kbuf + (size_t)MROWS*KVD;    // 2.10M
  u16* vtb  = vb   + (size_t)MROWS*KVD;    // 2.10M  -> total 67.1 MB
  u16* WpT  = WaT;   // W_attn^T dead after gemm1
  u16* yb   = xb;    // x_bf16 dead after gemm1
  float* out = (float*)d_out;

  cvt_x_kernel<<<(MROWS*EMB/4 + 255)/256, 256, 0, stream>>>(
      (const float4*)x, (ushort4*)xb, MROWS*EMB/4);
  transpose_w_kernel<<<dim3(QKVN/32, EMB/32), dim3(32, 8), 0, stream>>>(
      W_attn, WaT, EMB, QKVN);
  // gemm1: 256x192 tiles -> 16x16 = 256 blocks (1/CU)
  gemm_kernel<192, 4, 8, 3, 2, 3, 2, 3, true>
      <<<dim3(QKVN/192, MROWS/256), 512, 0, stream>>>(
      xb, WaT, b_attn, qkv, MROWS, QKVN, EMB);
  rope_kernel<<<MROWS, 256, 0, stream>>>(qkv, fc, fs, kbuf, vb);
  transpose_v_kernel<<<dim3(T_SEQ/32, HD/32, B_SZ*NKV), dim3(32, 8), 0, stream>>>(vb, vtb);
  transpose_w_kernel<<<dim3(EMB/32, EMB/32), dim3(32, 8), 0, stream>>>(
      W_proj, WpT, EMB, EMB);
  flash_kernel<<<dim3(B_SZ*NKV*(T_SEQ/16)), 256, 0, stream>>>(qkv, kbuf, vtb, yb);
  // gemm2: 256x128 tiles -> 16x16 = 256 blocks (1/CU; was 128 blocks in r1)
  gemm_kernel<128, 2, 4, 4, 2, 2, 1, 2, false>
      <<<dim3(EMB/128, MROWS/256), 512, 0, stream>>>(
      yb, WpT, nullptr, out, MROWS, EMB, EMB);
}

// Round 3
// 281.351 us; speedup vs baseline: 1.0995x; 1.0141x over previous
//
#include <hip/hip_runtime.h>
#include <cstdint>
#include <cstddef>

#define T_SEQ 2048
#define B_SZ  2
#define EMB   2048
#define NH    16
#define NKV   4
#define HD    128
#define KVD   512
#define QKVN  3072
#define MROWS (B_SZ*T_SEQ)

typedef __bf16 bf16x8 __attribute__((ext_vector_type(8)));
typedef float  f32x4  __attribute__((ext_vector_type(4)));
typedef short  s16x8  __attribute__((ext_vector_type(8)));
typedef unsigned short u16;

__device__ __forceinline__ u16 f2b(float f) {
  uint32_t u = __builtin_bit_cast(uint32_t, f);
  u += 0x7fffu + ((u >> 16) & 1u);      // RNE
  return (u16)(u >> 16);
}
__device__ __forceinline__ float b2f(u16 h) {
  return __builtin_bit_cast(float, (uint32_t)h << 16);
}
__device__ __forceinline__ bf16x8 ld_bf8(const u16* p) {
  return __builtin_bit_cast(bf16x8, *(const s16x8*)p);
}
__device__ __forceinline__ void glds16(const void* g, void* l) {
  __builtin_amdgcn_global_load_lds((const __attribute__((address_space(1))) void*)g,
                                   (__attribute__((address_space(3))) void*)l, 16, 0, 0);
}
template<int N> __device__ __forceinline__ void waitv() {
  if constexpr (N == 0) asm volatile("s_waitcnt vmcnt(0)" ::: "memory");
  else if constexpr (N == 2) asm volatile("s_waitcnt vmcnt(2)" ::: "memory");
  else if constexpr (N == 3) asm volatile("s_waitcnt vmcnt(3)" ::: "memory");
  __builtin_amdgcn_sched_barrier(0);
}

// ---------------- fp32 -> bf16 elementwise ----------------
__global__ void cvt_x_kernel(const float4* __restrict__ x, ushort4* __restrict__ xb, int n4) {
  int i = blockIdx.x*blockDim.x + threadIdx.x;
  if (i >= n4) return;
  float4 v = x[i];
  ushort4 o;
  o.x = f2b(v.x); o.y = f2b(v.y); o.z = f2b(v.z); o.w = f2b(v.w);
  xb[i] = o;
}

// ---------------- fp32 (R x C) -> bf16 transposed (C x R) ----------------
__global__ void transpose_w_kernel(const float* __restrict__ in, u16* __restrict__ out,
                                   int R, int C) {
  __shared__ float tile[32][33];
  int c0 = blockIdx.x*32, r0 = blockIdx.y*32;
  int tx = threadIdx.x, ty = threadIdx.y;
#pragma unroll
  for (int i = 0; i < 32; i += 8)
    tile[ty+i][tx] = in[(size_t)(r0+ty+i)*C + c0+tx];
  __syncthreads();
#pragma unroll
  for (int i = 0; i < 32; i += 8)
    out[(size_t)(c0+ty+i)*R + r0+tx] = f2b(tile[tx][ty+i]);
}

// ---------------- bf16 GEMM, 256xBN tile, 8-phase counted-vmcnt schedule ----
// (unchanged from r2 — verified: 256 blocks = 1/CU for both instantiations)
template<int BN, int WGN, int MF, int NF, int NF1, int SB, int SB1, int VMC, bool BF16_OUT>
__global__ __launch_bounds__(512, 2) void gemm_kernel(const u16* __restrict__ A,
        const u16* __restrict__ Bt, const float* __restrict__ bias,
        void* __restrict__ Cout, int M, int N, int K) {
  constexpr int MF2 = MF/2;
  __shared__ u16 As[2][256*64];
  __shared__ u16 Bs[2][BN*64];
  const int tid = threadIdx.x;
  const int w = tid >> 6, lane = tid & 63;
  const int quad = lane >> 4, lc = lane & 15;
  const int wrow = w / WGN, wcol = w % WGN;
  const int gx = gridDim.x;
  const int lin = blockIdx.y*gx + blockIdx.x;
  const int swz = (lin & 7)*32 + (lin >> 3);
  const int m0 = (swz / gx)*256, n0 = (swz % gx)*BN;

  f32x4 acc[MF][NF] = {};
  bf16x8 af[MF2][2], bfv[NF][2];

  int xoff[2];
#pragma unroll
  for (int ks = 0; ks < 2; ++ks) xoff[ks] = ((ks*4 + quad) ^ (lc & 7))*8;
  const int arow0 = (wrow*MF*16 + lc)*64;
  const int brow0 = (wcol*NF*16 + lc)*64;

  const int srb  = tid >> 3;
  const int spos = (tid & 7) ^ (srb & 7);
  const u16* sAp = A  + (size_t)(m0 + srb)*K + spos*8;
  const u16* sBp = Bt + (size_t)(n0 + srb)*K + spos*8;

#define STAGE_A(bf_, t_, h_) do { \
    glds16(sAp + (size_t)((h_)*2  )*64*K + (size_t)(t_)*64, &As[bf_][((h_)*2  )*4096 + w*512]); \
    glds16(sAp + (size_t)((h_)*2+1)*64*K + (size_t)(t_)*64, &As[bf_][((h_)*2+1)*4096 + w*512]); \
  } while (0)
#define STAGE_B(bf_, t_, p_) do { \
    _Pragma("unroll") for (int r = (p_) ? SB1 : 0; r < ((p_) ? SB : SB1); ++r) \
      glds16(sBp + (size_t)r*64*K + (size_t)(t_)*64, &Bs[bf_][r*4096 + w*512]); \
  } while (0)
#define LDAH(S_, h_) do { _Pragma("unroll") for (int i = 0; i < MF2; ++i) { \
    af[i][0] = ld_bf8((S_) + arow0 + ((h_)*MF2 + i)*1024 + xoff[0]); \
    af[i][1] = ld_bf8((S_) + arow0 + ((h_)*MF2 + i)*1024 + xoff[1]); } } while (0)
#define LDBG(S_, g_) do { _Pragma("unroll") for (int j = (g_) ? NF1 : 0; j < ((g_) ? NF : NF1); ++j) { \
    bfv[j][0] = ld_bf8((S_) + brow0 + j*1024 + xoff[0]); \
    bfv[j][1] = ld_bf8((S_) + brow0 + j*1024 + xoff[1]); } } while (0)
#define CL(h_, g_) do { _Pragma("unroll") for (int ks = 0; ks < 2; ++ks) \
    _Pragma("unroll") for (int i = 0; i < MF2; ++i) \
    _Pragma("unroll") for (int j = (g_) ? NF1 : 0; j < ((g_) ? NF : NF1); ++j) \
      acc[(h_)*MF2+i][j] = __builtin_amdgcn_mfma_f32_16x16x32_bf16( \
          af[i][ks], bfv[j][ks], acc[(h_)*MF2+i][j], 0, 0, 0); } while (0)
#define BARX()  __builtin_amdgcn_s_barrier()
#define SCHB()  __builtin_amdgcn_sched_barrier(0)
#define MFMAPH(h_, g_) do { BARX(); \
    asm volatile("s_waitcnt lgkmcnt(0)" ::: "memory"); SCHB(); \
    __builtin_amdgcn_s_setprio(1); CL(h_, g_); __builtin_amdgcn_s_setprio(0); \
  } while (0)

  const int NT = K >> 6;
  STAGE_B(0, 0, 0); STAGE_B(0, 0, 1);
  STAGE_A(0, 0, 0); STAGE_A(0, 0, 1);
  STAGE_B(1, 1, 0); STAGE_B(1, 1, 1);
  waitv<VMC>();
  BARX(); SCHB();

  for (int t0 = 0; t0 < NT-2; t0 += 2) {
    const u16 *a0 = As[0], *b0 = Bs[0], *a1 = As[1], *b1 = Bs[1];
    LDAH(a0, 0); LDBG(b0, 0); STAGE_A(1, t0+1, 0);
    MFMAPH(0, 0); BARX();
    LDBG(b0, 1); STAGE_A(1, t0+1, 1);
    MFMAPH(0, 1); BARX();
    LDAH(a0, 1); STAGE_B(0, t0+2, 0);
    MFMAPH(1, 0); BARX();
    STAGE_B(0, t0+2, 1);
    MFMAPH(1, 1);
    waitv<VMC>();
    BARX(); SCHB();
    LDAH(a1, 0); LDBG(b1, 0); STAGE_A(0, t0+2, 0);
    MFMAPH(0, 0); BARX();
    LDBG(b1, 1); STAGE_A(0, t0+2, 1);
    MFMAPH(0, 1); BARX();
    LDAH(a1, 1); STAGE_B(1, t0+3, 0);
    MFMAPH(1, 0); BARX();
    STAGE_B(1, t0+3, 1);
    MFMAPH(1, 1);
    waitv<VMC>();
    BARX(); SCHB();
  }
  {
    const u16 *a0 = As[0], *b0 = Bs[0], *a1 = As[1], *b1 = Bs[1];
    LDAH(a0, 0); LDBG(b0, 0); STAGE_A(1, NT-1, 0);
    MFMAPH(0, 0); BARX();
    LDBG(b0, 1); STAGE_A(1, NT-1, 1);
    MFMAPH(0, 1); BARX();
    LDAH(a0, 1);
    MFMAPH(1, 0); BARX();
    MFMAPH(1, 1);
    waitv<0>();
    BARX(); SCHB();
    LDAH(a1, 0); LDBG(b1, 0);
    MFMAPH(0, 0); BARX();
    LDBG(b1, 1);
    MFMAPH(0, 1); BARX();
    LDAH(a1, 1);
    MFMAPH(1, 0); BARX();
    MFMAPH(1, 1);
  }

#undef STAGE_A
#undef STAGE_B
#undef LDAH
#undef LDBG
#undef CL
#undef BARX
#undef SCHB
#undef MFMAPH

#pragma unroll
  for (int j = 0; j < NF; ++j) {
    int col = n0 + wcol*NF*16 + j*16 + lc;
    float bv = BF16_OUT ? bias[col] : 0.0f;
#pragma unroll
    for (int i = 0; i < MF; ++i) {
      int rowb = m0 + wrow*MF*16 + i*16 + quad*4;
#pragma unroll
      for (int r = 0; r < 4; ++r) {
        float v = acc[i][j][r] + bv;
        if (BF16_OUT) ((u16*)Cout)[(size_t)(rowb+r)*N + col] = f2b(v);
        else          ((float*)Cout)[(size_t)(rowb+r)*N + col] = v;
      }
    }
  }
}

// ---------------- RoPE on K and V (reference ropes V too, not Q) ----------------
__global__ void rope_kernel(const u16* __restrict__ qkv, const float* __restrict__ fc,
                            const float* __restrict__ fs, u16* __restrict__ kout,
                            u16* __restrict__ vout) {
  int tid = threadIdx.x;
  int row = blockIdx.x;             // b*T + t
  int i = tid & 63, kv = tid >> 6;  // pair index, kv head
  int t = row & (T_SEQ-1);
  const u16* p = qkv + (size_t)row*QKVN + EMB + kv*HD + 2*i;
  float ka = b2f(p[0]),   kb = b2f(p[1]);
  float va = b2f(p[KVD]), vb = b2f(p[KVD+1]);
  float c = fc[t*64+i], s = fs[t*64+i];
  size_t ob = (size_t)row*KVD + kv*HD + 2*i;
  kout[ob]   = f2b(ka*c - kb*s);
  kout[ob+1] = f2b(ka*s + kb*c);
  vout[ob]   = f2b(va*c - vb*s);
  vout[ob+1] = f2b(va*s + vb*c);
}

// ---------------- V (b,t,kv,d) -> Vt (b,kv,d,t) ----------------
__global__ void transpose_v_kernel(const u16* __restrict__ vb, u16* __restrict__ vtb) {
  __shared__ u16 tile[32][33];
  int bkv = blockIdx.z;
  int b = bkv >> 2, kv = bkv & 3;
  int d0 = blockIdx.y*32, t0 = blockIdx.x*32;
  int tx = threadIdx.x, ty = threadIdx.y;
#pragma unroll
  for (int i = 0; i < 32; i += 8)
    tile[ty+i][tx] = vb[(size_t)(b*T_SEQ + t0+ty+i)*KVD + kv*HD + d0 + tx];
  __syncthreads();
#pragma unroll
  for (int i = 0; i < 32; i += 8)
    vtb[(size_t)(bkv*HD + d0+ty+i)*T_SEQ + t0 + tx] = tile[tx][ty+i];
}

// ---------------- flash attention v5: double-buffered K/V, prefetch-early ----
// One 256-thread block per (b, kv-group, 16-query tile); 4 waves = 4 Q-heads
// sharing the staged K/V (GQA). v5 changes vs v4 (counters: MfmaUtil 20.7,
// VALUBusy 40, stage serialized between two barriers):
//  - K/V double-buffered; tile t+1's 8 glds16 issued at TOP of tile t, then
//    vmcnt(0) AFTER compute (loads had ~1500cy to land) + ONE barrier/tile.
//    Ledger: buf[nxt] last read in tile t-1; barrier(end t-1) protects the
//    overwrite; per-wave vmcnt(0) before barrier publishes cross-wave data.
//  - exp2 via __builtin_amdgcn_exp2f (raw v_exp_f32, not the ocml sequence).
//  - s_setprio(1) around QK and PV MFMA clusters (m191: helps independent
//    attn blocks).
__global__ __launch_bounds__(256, 2) void flash_kernel(const u16* __restrict__ qkv,
    const u16* __restrict__ kb, const u16* __restrict__ vtb, u16* __restrict__ yb) {
  constexpr int PP = 72;                 // P pitch: 144B rows, conflict-free pa reads
  __shared__ u16 Ks[2][64*128];          // 2 x 16 KB
  __shared__ u16 Vs[2][128*64];          // 2 x 16 KB
  __shared__ u16 Ps[4][16*PP];           // 9 KB
  const int tid = threadIdx.x;
  const int w = tid >> 6, lane = tid & 63;
  const int quad = lane >> 4, lc = lane & 15;
  const int bkv = blockIdx.x & 7;        // XCD-pinned (b,kv)
  const int r_  = blockIdx.x >> 3;       // 0..127
  const int b = bkv >> 2, kv = bkv & 3;
  const int h = kv*4 + w;                // wave = one head of the group
  const int qbase = (127 - r_)*16;       // heavy q-tiles dispatch first

  // Q frags (A-layout) for 16 queries of head h; no RoPE on Q
  bf16x8 qf[4];
  {
    const u16* qp = qkv + (size_t)(b*T_SEQ + qbase + lc)*QKVN + h*HD + quad*8;
#pragma unroll
    for (int ks = 0; ks < 4; ++ks) qf[ks] = ld_bf8(qp + ks*32);
  }

  f32x4 o[8] = {};
  float rs[4] = {0.f, 0.f, 0.f, 0.f};
  const u16* kbase = kb  + (size_t)b*T_SEQ*KVD + kv*HD;
  const u16* vbase = vtb + (size_t)bkv*HD*T_SEQ;
  const int nk = qbase + 16;
  const int nt = (nk + 63) >> 6;
  const float cs = 0.08838834764831845f * 1.4426950408889634f;  // scale * log2(e)
  u16* pw = Ps[w];

  // fixed per-thread staging source pointers (source-side XOR swizzle)
  const u16* kptr[4];
  const u16* vptr[4];
#pragma unroll
  for (int rr = 0; rr < 4; ++rr) {
    int krow = (rr*4 + w)*4 + (lane >> 4);
    int kcc  = (lane & 15) ^ (krow & 15);
    kptr[rr] = kbase + (size_t)krow*KVD + kcc*8;
    int vrow = (rr*4 + w)*8 + (lane >> 3);
    int vcc  = (lane & 7) ^ (vrow & 7);
    vptr[rr] = vbase + (size_t)vrow*T_SEQ + vcc*8;
  }

  // per-lane swizzled chunk offsets (hoisted out of the K-loop)
  int koff[4], voff[2];
#pragma unroll
  for (int ks = 0; ks < 4; ++ks) koff[ks] = lc*128 + (((ks*4 + quad) ^ lc)*8);
#pragma unroll
  for (int ks = 0; ks < 2; ++ks) voff[ks] = lc*64 + (((ks*4 + quad) ^ (lc & 7))*8);

  // prologue: stage tile 0 -> buf 0, publish
#pragma unroll
  for (int rr = 0; rr < 4; ++rr) glds16(kptr[rr], &Ks[0][(rr*4 + w)*512]);
#pragma unroll
  for (int rr = 0; rr < 4; ++rr) glds16(vptr[rr], &Vs[0][(rr*4 + w)*512]);
  asm volatile("s_waitcnt vmcnt(0)" ::: "memory");
  __builtin_amdgcn_sched_barrier(0);
  __builtin_amdgcn_s_barrier();
  __builtin_amdgcn_sched_barrier(0);

  for (int t = 0; t < nt; ++t) {
    const int cur = t & 1;
    // prefetch tile t+1 into the other buffer (protected by barrier(end t-1))
    if (t + 1 < nt) {
#pragma unroll
      for (int rr = 0; rr < 4; ++rr)
        glds16(kptr[rr] + (size_t)(t+1)*64*KVD, &Ks[cur^1][(rr*4 + w)*512]);
#pragma unroll
      for (int rr = 0; rr < 4; ++rr)
        glds16(vptr[rr] + (size_t)(t+1)*64,     &Vs[cur^1][(rr*4 + w)*512]);
    }
    const u16* ksb = Ks[cur];
    const u16* vsb = Vs[cur];
    const int k0 = t*64;

    // S = Q K^T : 16 queries x 64 keys
    f32x4 sc[4] = {};
    __builtin_amdgcn_s_setprio(1);
#pragma unroll
    for (int nt2 = 0; nt2 < 4; ++nt2)
#pragma unroll
      for (int ks = 0; ks < 4; ++ks) {
        bf16x8 kf = ld_bf8(ksb + nt2*16*128 + koff[ks]);
        sc[nt2] = __builtin_amdgcn_mfma_f32_16x16x32_bf16(qf[ks], kf, sc[nt2], 0, 0, 0);
      }
    __builtin_amdgcn_s_setprio(0);

    // softmax (m=0): p = exp2(s*cs); mask only on the diagonal/partial tiles
    if (k0 + 63 > qbase) {
#pragma unroll
      for (int nt2 = 0; nt2 < 4; ++nt2) {
        int key = k0 + nt2*16 + lc;
        int qrow = qbase + quad*4;
#pragma unroll
        for (int r = 0; r < 4; ++r) {
          float e = __builtin_amdgcn_exp2f(sc[nt2][r]*cs);
          float p = (key <= qrow + r) ? e : 0.0f;
          rs[r] += p;
          pw[(quad*4 + r)*PP + nt2*16 + lc] = f2b(p);
        }
      }
    } else {
#pragma unroll
      for (int nt2 = 0; nt2 < 4; ++nt2)
#pragma unroll
        for (int r = 0; r < 4; ++r) {
          float p = __builtin_amdgcn_exp2f(sc[nt2][r]*cs);
          rs[r] += p;
          pw[(quad*4 + r)*PP + nt2*16 + lc] = f2b(p);
        }
    }

    // P: C-layout -> A-layout via per-wave LDS roundtrip (intra-wave DS in-order)
    bf16x8 pa[2];
#pragma unroll
    for (int ks = 0; ks < 2; ++ks)
      pa[ks] = ld_bf8(pw + lc*PP + ks*32 + quad*8);

    // O += P V
    __builtin_amdgcn_s_setprio(1);
#pragma unroll
    for (int j = 0; j < 8; ++j)
#pragma unroll
      for (int ks = 0; ks < 2; ++ks) {
        bf16x8 vf = ld_bf8(vsb + j*16*64 + voff[ks]);
        o[j] = __builtin_amdgcn_mfma_f32_16x16x32_bf16(pa[ks], vf, o[j], 0, 0, 0);
      }
    __builtin_amdgcn_s_setprio(0);

    // publish prefetched tile: own loads drained, then block-wide sync
    asm volatile("s_waitcnt vmcnt(0)" ::: "memory");
    __builtin_amdgcn_sched_barrier(0);
    __builtin_amdgcn_s_barrier();
    __builtin_amdgcn_sched_barrier(0);
  }

  // epilogue: l-reduce over the 16 key-lanes, normalize, store
#pragma unroll
  for (int r = 0; r < 4; ++r) {
    float v = rs[r];
#pragma unroll
    for (int off2 = 8; off2 >= 1; off2 >>= 1)
      v += __shfl_xor(v, off2);
    float inv = 1.0f / v;
    size_t orow = (size_t)(b*T_SEQ + qbase + quad*4 + r)*EMB + h*HD;
#pragma unroll
    for (int j = 0; j < 8; ++j)
      yb[orow + j*16 + lc] = f2b(o[j][r]*inv);
  }
}

extern "C" void kernel_launch(void* const* d_in, const int* in_sizes, int n_in,
                              void* d_out, int out_size, void* d_ws, size_t ws_size,
                              hipStream_t stream) {
  const float* x      = (const float*)d_in[0];
  const float* W_attn = (const float*)d_in[1];
  const float* b_attn = (const float*)d_in[2];
  const float* W_proj = (const float*)d_in[3];
  const float* fc     = (const float*)d_in[4];
  const float* fs     = (const float*)d_in[5];

  u16* ws   = (u16*)d_ws;
  u16* xb   = ws;                          // 8.39M elems  (later aliased by yb)
  u16* WaT  = xb   + (size_t)MROWS*EMB;    // 6.29M        (later aliased by WpT)
  u16* qkv  = WaT  + (size_t)QKVN*EMB;     // 12.58M
  u16* kbuf = qkv  + (size_t)MROWS*QKVN;   // 2.10M
  u16* vb   = kbuf + (size_t)MROWS*KVD;    // 2.10M
  u16* vtb  = vb   + (size_t)MROWS*KVD;    // 2.10M  -> total 67.1 MB
  u16* WpT  = WaT;   // W_attn^T dead after gemm1
  u16* yb   = xb;    // x_bf16 dead after gemm1
  float* out = (float*)d_out;

  cvt_x_kernel<<<(MROWS*EMB/4 + 255)/256, 256, 0, stream>>>(
      (const float4*)x, (ushort4*)xb, MROWS*EMB/4);
  transpose_w_kernel<<<dim3(QKVN/32, EMB/32), dim3(32, 8), 0, stream>>>(
      W_attn, WaT, EMB, QKVN);
  // gemm1: 256x192 tiles -> 16x16 = 256 blocks (1/CU)
  gemm_kernel<192, 4, 8, 3, 2, 3, 2, 3, true>
      <<<dim3(QKVN/192, MROWS/256), 512, 0, stream>>>(
      xb, WaT, b_attn, qkv, MROWS, QKVN, EMB);
  rope_kernel<<<MROWS, 256, 0, stream>>>(qkv, fc, fs, kbuf, vb);
  transpose_v_kernel<<<dim3(T_SEQ/32, HD/32, B_SZ*NKV), dim3(32, 8), 0, stream>>>(vb, vtb);
  transpose_w_kernel<<<dim3(EMB/32, EMB/32), dim3(32, 8), 0, stream>>>(
      W_proj, WpT, EMB, EMB);
  flash_kernel<<<dim3(B_SZ*NKV*(T_SEQ/16)), 256, 0, stream>>>(qkv, kbuf, vtb, yb);
  // gemm2: 256x128 tiles -> 16x16 = 256 blocks (1/CU)
  gemm_kernel<128, 2, 4, 4, 2, 2, 1, 2, false>
      <<<dim3(EMB/128, MROWS/256), 512, 0, stream>>>(
      yb, WpT, nullptr, out, MROWS, EMB, EMB);
}